// Round 1
// baseline (138.815 us; speedup 1.0000x reference)
//
#include <hip/hip_runtime.h>

#define KN 8192

// ---------------------------------------------------------------------------
// Kernel B: partial ranks via brute-force counting.
// grid = 32 u-tiles x 4 v-tiles x 2 arrays = 256 blocks of 256 threads.
// rank[u] = #{ v : x[v] < x[u]  ||  (x[v]==x[u] && v<u) }   (stable argsort tie-break)
// ---------------------------------------------------------------------------
constexpr int NBLK_V = 4;            // v-tiles per array
constexpr int VT = KN / NBLK_V;      // 2048 v per block

__global__ __launch_bounds__(256) void rank_partial(const float* __restrict__ X,
                                                    const float* __restrict__ Xh,
                                                    int* __restrict__ rank_a,
                                                    int* __restrict__ rank_b) {
    int blk = blockIdx.x;
    int arr = blk & 1;
    int vt  = (blk >> 1) & (NBLK_V - 1);
    int ut  = blk >> 3;                       // 0..31
    const float* src = arr ? Xh : X;
    int* rnk         = arr ? rank_b : rank_a;

    int u = ut * 256 + threadIdx.x;
    float xu = src[u];

    __shared__ float tile[256];
    int cnt = 0;
    int v0 = vt * VT;
    for (int t0 = v0; t0 < v0 + VT; t0 += 256) {
        __syncthreads();
        tile[threadIdx.x] = src[t0 + threadIdx.x];
        __syncthreads();
#pragma unroll 8
        for (int jj = 0; jj < 256; ++jj) {
            float xv = tile[jj];          // broadcast LDS read (jj wave-uniform)
            int v = t0 + jj;
            cnt += (xv < xu) ? 1 : 0;
            cnt += (xv == xu && v < u) ? 1 : 0;   // stable tie-break
        }
    }
    atomicAdd(&rnk[u], cnt);
}

// ---------------------------------------------------------------------------
// Kernel C: scatter a[rank[u]] = u  (argsort is the inverse permutation of rank)
// grid = 64 blocks x 256 (first 8192 threads -> a, rest -> b)
// ---------------------------------------------------------------------------
__global__ __launch_bounds__(256) void scatter_k(const int* __restrict__ rank_a,
                                                 const int* __restrict__ rank_b,
                                                 int* __restrict__ a,
                                                 int* __restrict__ b) {
    int u = blockIdx.x * 256 + threadIdx.x;
    if (u < KN) {
        a[rank_a[u]] = u;
    } else {
        int w = u - KN;
        b[rank_b[w]] = w;
    }
}

// ---------------------------------------------------------------------------
// Kernel D: count discordant unordered pairs (i<j) between sequences a and b.
// Triangular tiling: 32 tiles of 256 -> 528 blocks of 256 threads.
// discordant  <=>  sign(a[i]-a[j]) != sign(b[i]-b[j])  <=>  ((da)^(db)) < 0
// ---------------------------------------------------------------------------
__global__ __launch_bounds__(256) void pair_count(const int* __restrict__ a,
                                                  const int* __restrict__ b,
                                                  unsigned int* __restrict__ count) {
    constexpr int TS = 256;
    constexpr int T  = KN / TS;   // 32 tiles, 32*33/2 = 528 blocks

    int blk = blockIdx.x;
    int p = 0, rem = blk;
    while (rem >= T - p) { rem -= T - p; ++p; }   // wave-uniform decode
    int q = p + rem;                              // p <= q

    __shared__ int qa[TS], qb[TS];
    int tid = threadIdx.x;

    int i  = p * TS + tid;
    int ai = a[i], bi = b[i];
    qa[tid] = a[q * TS + tid];
    qb[tid] = b[q * TS + tid];
    __syncthreads();

    int cnt = 0;
    int jstart = (p == q) ? tid + 1 : 0;
    for (int j = jstart; j < TS; ++j) {
        cnt += (((ai - qa[j]) ^ (bi - qb[j])) < 0) ? 1 : 0;
    }

    // wave64 shuffle reduction, one atomic per wave
    for (int off = 32; off; off >>= 1) cnt += __shfl_down(cnt, off);
    if ((tid & 63) == 0) atomicAdd(count, (unsigned int)cnt);
}

// ---------------------------------------------------------------------------
// Kernel E: finalize.  ndisordered = 2*D (each unordered pair counted twice).
// ---------------------------------------------------------------------------
__global__ void finalize_k(const unsigned int* __restrict__ count,
                           float* __restrict__ out) {
    out[0] = 2.0f * (float)(*count) / ((float)KN * (float)(KN - 1));
}

// ---------------------------------------------------------------------------
// Workspace layout (all offsets in bytes):
//   0      : rank_a[8192]  (int, zeroed)
//   32768  : rank_b[8192]  (int, zeroed)
//   65536  : count         (uint, zeroed)
//   69632  : a[8192]       (int)
//   102400 : b[8192]       (int)
// total 135168 bytes
// ---------------------------------------------------------------------------
extern "C" void kernel_launch(void* const* d_in, const int* in_sizes, int n_in,
                              void* d_out, int out_size, void* d_ws, size_t ws_size,
                              hipStream_t stream) {
    const float* X  = (const float*)d_in[0];
    const float* Xh = (const float*)d_in[1];

    char* ws = (char*)d_ws;
    int* rank_a = (int*)(ws);
    int* rank_b = (int*)(ws + 32768);
    unsigned int* count = (unsigned int*)(ws + 65536);
    int* a = (int*)(ws + 69632);
    int* b = (int*)(ws + 102400);

    // zero rank accumulators + count (d_ws is re-poisoned to 0xAA each call)
    hipMemsetAsync(d_ws, 0, 65536 + 64, stream);

    rank_partial<<<dim3(256), dim3(256), 0, stream>>>(X, Xh, rank_a, rank_b);
    scatter_k  <<<dim3(64),  dim3(256), 0, stream>>>(rank_a, rank_b, a, b);
    pair_count <<<dim3(528), dim3(256), 0, stream>>>(a, b, count);
    finalize_k <<<dim3(1),   dim3(1),   0, stream>>>(count, (float*)d_out);
}

// Round 2
// 99.018 us; speedup vs baseline: 1.4019x; 1.4019x over previous
//
#include <hip/hip_runtime.h>

#define KN 8192

// Monotone float -> uint32 transform (order-preserving), packed with the
// element index into a distinct 64-bit key. Lexicographic (value, index)
// order == jnp stable argsort order. index < 8192 = 2^13.
__device__ __forceinline__ unsigned long long make_key(float x, int idx) {
    unsigned int u = __float_as_uint(x);
    u ^= (unsigned int)((int)u >> 31) | 0x80000000u;  // neg: flip all; pos: set sign
    return ((unsigned long long)u << 13) | (unsigned int)idx;
}

// ---------------------------------------------------------------------------
// Kernel 1: partial ranks, brute force with u64 keys + 4x register blocking.
// rank[u] = #{ v : key[v] < key[u] }  (exact; keys distinct)
// grid = 8 u-tiles x 64 v-tiles x 2 arrays = 1024 blocks of 256 threads.
// Per block: 1024 u x 128 v. Inner op: 1 LDS b64 broadcast + 4x(cmp_u64+addc).
// ---------------------------------------------------------------------------
constexpr int UT  = 1024;        // u per block (4 per thread)
constexpr int VC  = 128;         // v per block
constexpr int NVT = KN / VC;     // 64 v-tiles

__global__ __launch_bounds__(256) void rank_partial(const float* __restrict__ X,
                                                    const float* __restrict__ Xh,
                                                    int* __restrict__ rank_a,
                                                    int* __restrict__ rank_b) {
    int blk = blockIdx.x;
    int arr = blk & 1;
    int vt  = (blk >> 1) & (NVT - 1);
    int ut  = blk >> 7;                       // blk / (2*64), 0..7
    const float* src = arr ? Xh : X;
    int* rnk         = arr ? rank_b : rank_a;

    int tid = threadIdx.x;

    // 4 u's per thread, coalesced
    int u0 = ut * UT + tid;
    unsigned long long ku0 = make_key(src[u0],       u0);
    unsigned long long ku1 = make_key(src[u0 + 256], u0 + 256);
    unsigned long long ku2 = make_key(src[u0 + 512], u0 + 512);
    unsigned long long ku3 = make_key(src[u0 + 768], u0 + 768);

    __shared__ unsigned long long tile[VC];
    if (tid < VC) {
        int v = vt * VC + tid;
        tile[tid] = make_key(src[v], v);
    }
    __syncthreads();

    int c0 = 0, c1 = 0, c2 = 0, c3 = 0;
#pragma unroll 16
    for (int jj = 0; jj < VC; ++jj) {
        unsigned long long kv = tile[jj];   // wave-uniform -> LDS broadcast
        c0 += (kv < ku0);
        c1 += (kv < ku1);
        c2 += (kv < ku2);
        c3 += (kv < ku3);
    }

    atomicAdd(&rnk[u0],       c0);
    atomicAdd(&rnk[u0 + 256], c1);
    atomicAdd(&rnk[u0 + 512], c2);
    atomicAdd(&rnk[u0 + 768], c3);
}

// ---------------------------------------------------------------------------
// Kernel 2: scatter both argsorts.  a[rank_a[u]] = u ; b[rank_b[u]] = u
// ---------------------------------------------------------------------------
__global__ __launch_bounds__(256) void scatter_k(const int* __restrict__ rank_a,
                                                 const int* __restrict__ rank_b,
                                                 int* __restrict__ a,
                                                 int* __restrict__ b) {
    int u = blockIdx.x * 256 + threadIdx.x;
    a[rank_a[u]] = u;
    b[rank_b[u]] = u;
}

// ---------------------------------------------------------------------------
// Kernel 3: e[a[i]] = b[i].
// D (= ndisordered/2) equals the inversion count of sequence e:
// pairs (i,j) discordant between sequences a,b  <=>  inversions of b composed
// with a^-1, realized as e[k] with k = a[i], e[k] = b[i].
// ---------------------------------------------------------------------------
__global__ __launch_bounds__(256) void gather_e(const int* __restrict__ a,
                                                const int* __restrict__ b,
                                                int* __restrict__ e) {
    int i = blockIdx.x * 256 + threadIdx.x;
    e[a[i]] = b[i];
}

// ---------------------------------------------------------------------------
// Kernel 4: inversion count of e.  Triangular 256-tiles: 32*33/2 = 528 blocks.
// Off-diagonal inner op: int4 LDS broadcast + 4x(cmp+addc)  (2 VALU / pair).
// ---------------------------------------------------------------------------
__global__ __launch_bounds__(256) void inv_count(const int* __restrict__ e,
                                                 unsigned int* __restrict__ count) {
    constexpr int TS = 256;
    constexpr int T  = KN / TS;   // 32

    int blk = blockIdx.x;
    int p = 0, rem = blk;
    while (rem >= T - p) { rem -= T - p; ++p; }   // wave-uniform decode
    int q = p + rem;                              // p <= q ; k-tile p, l-tile q

    __shared__ int le[TS];
    int tid = threadIdx.x;

    int ek = e[p * TS + tid];
    le[tid] = e[q * TS + tid];
    __syncthreads();

    int cnt = 0;
    if (p == q) {
        for (int j = tid + 1; j < TS; ++j) cnt += (ek > le[j]);
    } else {
        const int4* le4 = (const int4*)le;
#pragma unroll 8
        for (int j4 = 0; j4 < TS / 4; ++j4) {
            int4 v = le4[j4];                 // wave-uniform -> ds_read_b128 broadcast
            cnt += (ek > v.x) + (ek > v.y) + (ek > v.z) + (ek > v.w);
        }
    }

    for (int off = 32; off; off >>= 1) cnt += __shfl_down(cnt, off);
    if ((tid & 63) == 0) atomicAdd(count, (unsigned int)cnt);
}

// ---------------------------------------------------------------------------
// Kernel 5: finalize. ndisordered = 2*D.
// ---------------------------------------------------------------------------
__global__ void finalize_k(const unsigned int* __restrict__ count,
                           float* __restrict__ out) {
    out[0] = 2.0f * (float)(*count) / ((float)KN * (float)(KN - 1));
}

// ---------------------------------------------------------------------------
// Workspace layout (bytes):
//   0      : rank_a[8192] int   (zeroed)
//   32768  : rank_b[8192] int   (zeroed)
//   65536  : count uint         (zeroed)
//   69632  : a[8192] int
//   102400 : b[8192] int
//   135168 : e[8192] int
// total 167936 bytes
// ---------------------------------------------------------------------------
extern "C" void kernel_launch(void* const* d_in, const int* in_sizes, int n_in,
                              void* d_out, int out_size, void* d_ws, size_t ws_size,
                              hipStream_t stream) {
    const float* X  = (const float*)d_in[0];
    const float* Xh = (const float*)d_in[1];

    char* ws = (char*)d_ws;
    int* rank_a = (int*)(ws);
    int* rank_b = (int*)(ws + 32768);
    unsigned int* count = (unsigned int*)(ws + 65536);
    int* a = (int*)(ws + 69632);
    int* b = (int*)(ws + 102400);
    int* e = (int*)(ws + 135168);

    hipMemsetAsync(d_ws, 0, 65536 + 64, stream);   // zero rank accumulators + count

    rank_partial<<<dim3(1024), dim3(256), 0, stream>>>(X, Xh, rank_a, rank_b);
    scatter_k   <<<dim3(32),   dim3(256), 0, stream>>>(rank_a, rank_b, a, b);
    gather_e    <<<dim3(32),   dim3(256), 0, stream>>>(a, b, e);
    inv_count   <<<dim3(528),  dim3(256), 0, stream>>>(e, count);
    finalize_k  <<<dim3(1),    dim3(1),   0, stream>>>(count, (float*)d_out);
}

// Round 3
// 78.628 us; speedup vs baseline: 1.7655x; 1.2593x over previous
//
#include <hip/hip_runtime.h>

#define KN 8192

// Monotone float -> uint32 transform (order-preserving), packed with the
// element index into a distinct 64-bit key. Lexicographic (value, index)
// order == jnp stable argsort order. index < 8192 = 2^13.
// 64-bit is REQUIRED: expected float32 collisions among 8192 N(0,1) samples
// is ~1 (birthday: 3.3e7 pairs x ~3.4e-8 per-pair), so value-only ranks
// would produce duplicate ranks and a broken scatter.
__device__ __forceinline__ unsigned long long make_key(float x, int idx) {
    unsigned int u = __float_as_uint(x);
    u ^= (unsigned int)((int)u >> 31) | 0x80000000u;  // neg: flip all; pos: set sign
    return ((unsigned long long)u << 13) | (unsigned int)idx;
}

// ---------------------------------------------------------------------------
// Kernel 1: partial ranks, brute force, NO atomics.
// rank[u] = #{ v : key[v] < key[u] }  (keys distinct)
// grid = 8 u-tiles x 64 v-tiles x 2 arrays = 1024 blocks of 256 threads.
// Per block: 1024 u (4/thread) x 128 v.
// Partials: part[(arr*NVT + vt)*KN + u]  -- each block owns a disjoint slice.
// ---------------------------------------------------------------------------
constexpr int UT  = 1024;        // u per block
constexpr int VC  = 128;         // v per block
constexpr int NVT = KN / VC;     // 64 v-tiles

__global__ __launch_bounds__(256) void rank_partial(const float* __restrict__ X,
                                                    const float* __restrict__ Xh,
                                                    int* __restrict__ part) {
    int blk = blockIdx.x;
    int arr = blk & 1;
    int vt  = (blk >> 1) & (NVT - 1);
    int ut  = blk >> 7;                       // blk / (2*NVT), 0..7
    const float* src = arr ? Xh : X;

    int tid = threadIdx.x;
    int u0 = ut * UT + tid;

    unsigned long long ku0 = make_key(src[u0],       u0);
    unsigned long long ku1 = make_key(src[u0 + 256], u0 + 256);
    unsigned long long ku2 = make_key(src[u0 + 512], u0 + 512);
    unsigned long long ku3 = make_key(src[u0 + 768], u0 + 768);

    __shared__ unsigned long long tile[VC];
    if (tid < VC) {
        int v = vt * VC + tid;
        tile[tid] = make_key(src[v], v);
    }
    __syncthreads();

    int c0 = 0, c1 = 0, c2 = 0, c3 = 0;
#pragma unroll 8
    for (int jj = 0; jj < VC; ++jj) {
        unsigned long long kv = tile[jj];   // wave-uniform -> LDS broadcast
        c0 += (kv < ku0);
        c1 += (kv < ku1);
        c2 += (kv < ku2);
        c3 += (kv < ku3);
    }

    int base = (arr * NVT + vt) * KN + u0;   // disjoint per block, coalesced
    part[base]       = c0;
    part[base + 256] = c1;
    part[base + 512] = c2;
    part[base + 768] = c3;
}

// ---------------------------------------------------------------------------
// Kernel 2: reduce partials -> rank, then scatter argsort in-place:
//   a[rank_a[u]] = u ; b[rank_b[u]] = u.
// grid = 64 blocks x 256  (threads 0..8191 -> array a, 8192..16383 -> b)
// ---------------------------------------------------------------------------
__global__ __launch_bounds__(256) void reduce_scatter(const int* __restrict__ part,
                                                      int* __restrict__ a,
                                                      int* __restrict__ b) {
    int t = blockIdx.x * 256 + threadIdx.x;   // 0..16383
    int arr = t >> 13;
    int u   = t & (KN - 1);

    const int* p = part + (arr * NVT) * KN + u;
    int r = 0;
#pragma unroll 8
    for (int vt = 0; vt < NVT; ++vt) r += p[vt * KN];   // coalesced across threads

    if (arr == 0) a[r] = u; else b[r] = u;
}

// ---------------------------------------------------------------------------
// Kernel 3: e[a[i]] = b[i].  Inversions of e == D == ndisordered/2.
// ---------------------------------------------------------------------------
__global__ __launch_bounds__(256) void gather_e(const int* __restrict__ a,
                                                const int* __restrict__ b,
                                                int* __restrict__ e) {
    int i = blockIdx.x * 256 + threadIdx.x;
    e[a[i]] = b[i];
}

// ---------------------------------------------------------------------------
// Kernel 4: inversion count of e. Triangular 256-tiles: 32*33/2 = 528 blocks.
// Off-diagonal: int4 LDS broadcast + 4x(cmp+addc). Block partial -> inv_part.
// ---------------------------------------------------------------------------
__global__ __launch_bounds__(256) void inv_count(const int* __restrict__ e,
                                                 int* __restrict__ inv_part) {
    constexpr int TS = 256;
    constexpr int T  = KN / TS;   // 32

    int blk = blockIdx.x;
    int p = 0, rem = blk;
    while (rem >= T - p) { rem -= T - p; ++p; }   // wave-uniform decode
    int q = p + rem;                              // p <= q

    __shared__ int le[TS];
    __shared__ int wsum[4];
    int tid = threadIdx.x;

    int ek = e[p * TS + tid];
    le[tid] = e[q * TS + tid];
    __syncthreads();

    int cnt = 0;
    if (p == q) {
        for (int j = tid + 1; j < TS; ++j) cnt += (ek > le[j]);
    } else {
        const int4* le4 = (const int4*)le;
#pragma unroll 8
        for (int j4 = 0; j4 < TS / 4; ++j4) {
            int4 v = le4[j4];                 // wave-uniform -> ds_read_b128 broadcast
            cnt += (ek > v.x) + (ek > v.y) + (ek > v.z) + (ek > v.w);
        }
    }

    for (int off = 32; off; off >>= 1) cnt += __shfl_down(cnt, off);
    if ((tid & 63) == 0) wsum[tid >> 6] = cnt;
    __syncthreads();
    if (tid == 0) inv_part[blk] = wsum[0] + wsum[1] + wsum[2] + wsum[3];
}

// ---------------------------------------------------------------------------
// Kernel 5: finalize. Sum 528 block partials; ndisordered = 2*D.
// ---------------------------------------------------------------------------
__global__ __launch_bounds__(256) void finalize_k(const int* __restrict__ inv_part,
                                                  float* __restrict__ out) {
    __shared__ int wsum[4];
    int tid = threadIdx.x;
    int cnt = 0;
    for (int i = tid; i < 528; i += 256) cnt += inv_part[i];
    for (int off = 32; off; off >>= 1) cnt += __shfl_down(cnt, off);
    if ((tid & 63) == 0) wsum[tid >> 6] = cnt;
    __syncthreads();
    if (tid == 0) {
        float D = (float)(wsum[0] + wsum[1] + wsum[2] + wsum[3]);
        out[0] = 2.0f * D / ((float)KN * (float)(KN - 1));
    }
}

// ---------------------------------------------------------------------------
// Workspace layout (bytes). Every word is written before it is read, so the
// harness 0xAA poison needs no memset.
//   0        : part[2*64*8192] int   (4 MiB)
//   4194304  : a[8192] int
//   4227072  : b[8192] int
//   4259840  : e[8192] int
//   4292608  : inv_part[528] int
// total ~4.3 MiB
// ---------------------------------------------------------------------------
extern "C" void kernel_launch(void* const* d_in, const int* in_sizes, int n_in,
                              void* d_out, int out_size, void* d_ws, size_t ws_size,
                              hipStream_t stream) {
    const float* X  = (const float*)d_in[0];
    const float* Xh = (const float*)d_in[1];

    char* ws = (char*)d_ws;
    int* part     = (int*)(ws);
    int* a        = (int*)(ws + 4194304);
    int* b        = (int*)(ws + 4227072);
    int* e        = (int*)(ws + 4259840);
    int* inv_part = (int*)(ws + 4292608);

    rank_partial  <<<dim3(1024), dim3(256), 0, stream>>>(X, Xh, part);
    reduce_scatter<<<dim3(64),   dim3(256), 0, stream>>>(part, a, b);
    gather_e      <<<dim3(32),   dim3(256), 0, stream>>>(a, b, e);
    inv_count     <<<dim3(528),  dim3(256), 0, stream>>>(e, inv_part);
    finalize_k    <<<dim3(1),    dim3(256), 0, stream>>>(inv_part, (float*)d_out);
}